// Round 1
// baseline (349.247 us; speedup 1.0000x reference)
//
#include <hip/hip_runtime.h>
#include <hip/hip_bf16.h>

// ---------------------------------------------------------------------------
// CrossAttention block: softmax(QK^T/sqrt(d)) V, out-proj, residual, LayerNorm
// B=2, N=2048, C=768, H=12, Dh=64.  All GEMM-shaped compute in bf16 MFMA
// (mfma_f32_16x16x32_bf16), fp32 accumulation, fp32 LayerNorm epilogue.
// ---------------------------------------------------------------------------

typedef unsigned short ushort_t;
typedef __bf16 bf16x8 __attribute__((ext_vector_type(8)));
typedef float  f32x4  __attribute__((ext_vector_type(4)));

constexpr int C_DIM  = 768;
constexpr int HEADS  = 12;
constexpr int DH     = 64;
constexpr int BATCH  = 2;
constexpr int SEQ    = 2048;
constexpr int MTOT   = BATCH * SEQ;      // 4096 rows
constexpr float EPS  = 1e-5f;
constexpr float SCALE = 0.125f;          // Dh^-0.5 = 1/8

// workspace layout (bytes)
constexpr size_t SZ_X = (size_t)MTOT * C_DIM;   // 3,145,728 elements
constexpr size_t SZ_W = (size_t)C_DIM * C_DIM;  // 589,824 elements
constexpr size_t B_XQ  = 0;
constexpr size_t B_XK  = B_XQ  + SZ_X * 2;
constexpr size_t B_XV  = B_XK  + SZ_X * 2;
constexpr size_t B_WQT = B_XV  + SZ_X * 2;
constexpr size_t B_WKT = B_WQT + SZ_W * 2;
constexpr size_t B_WVT = B_WKT + SZ_W * 2;
constexpr size_t B_WOT = B_WVT + SZ_W * 2;
constexpr size_t B_QH  = B_WOT + SZ_W * 2;      // [B,H,N,DH] bf16
constexpr size_t B_KH  = B_QH  + SZ_X * 2;      // [B,H,N,DH] bf16
constexpr size_t B_VT  = B_KH  + SZ_X * 2;      // [B,H,DH,N] bf16 (transposed!)
constexpr size_t B_O   = B_VT  + SZ_X * 2;      // [MTOT,C] bf16 attn output
constexpr size_t B_XR  = B_O   + SZ_X * 2;      // [MTOT,C] fp32 pre-LN

__device__ __forceinline__ ushort_t f2bf(float f) {
  __hip_bfloat16 h = __float2bfloat16(f);
  return __builtin_bit_cast(unsigned short, h);
}

// async global->LDS, 16B per lane.  LDS dest must be linear (base + lane*16).
__device__ __forceinline__ void gload_lds16(const void* g, void* l) {
  __builtin_amdgcn_global_load_lds(
      (const __attribute__((address_space(1))) unsigned int*)g,
      (__attribute__((address_space(3))) unsigned int*)l,
      16, 0, 0);
}

// ---------------------------------------------------------------------------
// 1) fp32 -> bf16 elementwise convert (vectorized float4 -> ushort4)
// ---------------------------------------------------------------------------
__global__ __launch_bounds__(256) void cvt_f32_to_bf16(
    const float* __restrict__ src, ushort_t* __restrict__ dst, int n4) {
  int i = blockIdx.x * 256 + threadIdx.x;
  if (i >= n4) return;
  float4 v = ((const float4*)src)[i];
  ushort4 o;
  o.x = f2bf(v.x); o.y = f2bf(v.y); o.z = f2bf(v.z); o.w = f2bf(v.w);
  ((ushort4*)dst)[i] = o;
}

// ---------------------------------------------------------------------------
// 2) transpose+convert the 4 weight matrices:  Wt[n][k] = W[k][n]  (bf16)
//    so GEMM B-fragments become contiguous 16B reads.
// ---------------------------------------------------------------------------
__global__ __launch_bounds__(256) void wtrans_kernel(
    const float* __restrict__ W0, const float* __restrict__ W1,
    const float* __restrict__ W2, const float* __restrict__ W3,
    ushort_t* T0, ushort_t* T1, ushort_t* T2, ushort_t* T3) {
  const float* W = blockIdx.z == 0 ? W0 : blockIdx.z == 1 ? W1 : blockIdx.z == 2 ? W2 : W3;
  ushort_t*    T = blockIdx.z == 0 ? T0 : blockIdx.z == 1 ? T1 : blockIdx.z == 2 ? T2 : T3;
  __shared__ float tile[32][33];   // +1 pad: conflict-free transpose
  int tx = threadIdx.x & 31, ty = threadIdx.x >> 5;   // 32 x 8
  int x0 = blockIdx.x * 32, y0 = blockIdx.y * 32;
#pragma unroll
  for (int i = 0; i < 32; i += 8)
    tile[ty + i][tx] = W[(size_t)(y0 + ty + i) * C_DIM + x0 + tx];
  __syncthreads();
#pragma unroll
  for (int i = 0; i < 32; i += 8)
    T[(size_t)(x0 + ty + i) * C_DIM + y0 + tx] = f2bf(tile[tx][ty + i]);
}

// ---------------------------------------------------------------------------
// GEMM mainloop: C[128x128] = A[128xK] * Bt[128xK]^T, K=768, BK=32.
// 4 waves (2x2), each wave 64x64 (4x4 frags of 16x16x32 MFMA).
// A/B tiles staged via global_load_lds (16B/lane), [128][32] bf16 row-major.
// Fragment maps (16x16x32): A: lane l reads A[l&15][(l>>4)*8 + j]
//                           B: lane l reads Bt[l&15][(l>>4)*8 + j]
//                           C: row=(l>>4)*4+reg, col=l&15
// ---------------------------------------------------------------------------
__device__ __forceinline__ void gemm128_mainloop(
    const ushort_t* __restrict__ A, const ushort_t* __restrict__ Bt,
    int rowBase, int colBase, ushort_t* ldsA, ushort_t* ldsB, f32x4 acc[4][4]) {
  const int tid = threadIdx.x;
  const int wave = tid >> 6, lane = tid & 63;
  const int wr = wave >> 1, wc = wave & 1;
  const int lrow = lane & 15, lk = lane >> 4;
  const int sr = tid >> 2, sk = (tid & 3) * 8;   // staging: row tid/4, 8-elem seg
  const int K = C_DIM;

  const ushort_t* ga0 = A  + (size_t)(rowBase + sr)      * K + sk;
  const ushort_t* ga1 = A  + (size_t)(rowBase + 64 + sr) * K + sk;
  const ushort_t* gb0 = Bt + (size_t)(colBase + sr)      * K + sk;
  const ushort_t* gb1 = Bt + (size_t)(colBase + 64 + sr) * K + sk;
  ushort_t* la = ldsA + sr * 32 + sk;            // byte offset tid*16 (linear)
  ushort_t* lb = ldsB + sr * 32 + sk;

  for (int kt = 0; kt < K; kt += 32) {
    gload_lds16(ga0 + kt, la);
    gload_lds16(ga1 + kt, la + 64 * 32);
    gload_lds16(gb0 + kt, lb);
    gload_lds16(gb1 + kt, lb + 64 * 32);
    asm volatile("s_waitcnt vmcnt(0)" ::: "memory");
    __syncthreads();
    bf16x8 af[4], bfr[4];
#pragma unroll
    for (int m = 0; m < 4; m++)
      af[m] = *(const bf16x8*)(ldsA + (wr * 64 + m * 16 + lrow) * 32 + lk * 8);
#pragma unroll
    for (int n = 0; n < 4; n++)
      bfr[n] = *(const bf16x8*)(ldsB + (wc * 64 + n * 16 + lrow) * 32 + lk * 8);
#pragma unroll
    for (int m = 0; m < 4; m++)
#pragma unroll
      for (int n = 0; n < 4; n++)
        acc[m][n] = __builtin_amdgcn_mfma_f32_16x16x32_bf16(af[m], bfr[n], acc[m][n], 0, 0, 0);
    __syncthreads();
  }
}

// ---------------------------------------------------------------------------
// 3) fused QKV projection.  grid = (6 colTiles, 32 rowTiles, 3 matrices)
//    writes q,k -> [B,H,N,DH] bf16,  v -> [B,H,DH,N] bf16 (transposed)
// ---------------------------------------------------------------------------
__global__ __launch_bounds__(256) void gemm_qkv_kernel(
    const ushort_t* __restrict__ Xq, const ushort_t* __restrict__ Xk,
    const ushort_t* __restrict__ Xv,
    const ushort_t* __restrict__ Wqt, const ushort_t* __restrict__ Wkt,
    const ushort_t* __restrict__ Wvt,
    const float* __restrict__ bq, const float* __restrict__ bk,
    const float* __restrict__ bv,
    ushort_t* Qh, ushort_t* Kh, ushort_t* Vt) {
  const int mat = blockIdx.z;
  const ushort_t* A  = mat == 0 ? Xq  : mat == 1 ? Xk  : Xv;
  const ushort_t* Bt = mat == 0 ? Wqt : mat == 1 ? Wkt : Wvt;
  const float* bias  = mat == 0 ? bq  : mat == 1 ? bk  : bv;

  __shared__ __align__(16) ushort_t ldsA[128 * 32];
  __shared__ __align__(16) ushort_t ldsB[128 * 32];

  const int rowBase = blockIdx.y * 128;
  const int colBase = blockIdx.x * 128;
  f32x4 acc[4][4];
#pragma unroll
  for (int m = 0; m < 4; m++)
#pragma unroll
    for (int n = 0; n < 4; n++)
#pragma unroll
      for (int r = 0; r < 4; r++) acc[m][n][r] = 0.f;

  gemm128_mainloop(A, Bt, rowBase, colBase, ldsA, ldsB, acc);

  const int lane = threadIdx.x & 63, wave = threadIdx.x >> 6;
  const int wr = wave >> 1, wc = wave & 1;
  const int lrow = lane & 15, lk = lane >> 4;

  __hip_bfloat16* dqk = (__hip_bfloat16*)(mat == 0 ? Qh : Kh);
  __hip_bfloat16* dvt = (__hip_bfloat16*)Vt;
#pragma unroll
  for (int n = 0; n < 4; n++) {
    const int col = colBase + wc * 64 + n * 16 + lrow;
    const float bval = bias[col];
    const int hh = col >> 6, dd = col & 63;
#pragma unroll
    for (int m = 0; m < 4; m++) {
#pragma unroll
      for (int r = 0; r < 4; r++) {
        const int row = rowBase + wr * 64 + m * 16 + lk * 4 + r;
        const int bb = row >> 11, nn = row & 2047;
        const float val = acc[m][n][r] + bval;
        if (mat < 2) {
          dqk[(((size_t)(bb * HEADS + hh) * SEQ + nn) << 6) + dd] = __float2bfloat16(val);
        } else {
          dvt[((size_t)(bb * HEADS + hh) * DH + dd) * SEQ + nn] = __float2bfloat16(val);
        }
      }
    }
  }
}

// ---------------------------------------------------------------------------
// 4) flash-style attention.  grid = (32 qTiles, 24 bh).  4 waves x 16 q-rows.
//    K/V read directly from global (L2-resident, 256KB/head each).
//    P transposed acc-layout -> A-frag-layout through XOR-swizzled LDS.
// ---------------------------------------------------------------------------
__global__ __launch_bounds__(256) void attn_kernel(
    const ushort_t* __restrict__ Qh, const ushort_t* __restrict__ Kh,
    const ushort_t* __restrict__ Vt, ushort_t* __restrict__ O) {
  const int qt = blockIdx.x;          // 0..31
  const int bh = blockIdx.y;          // 0..23
  const int b = bh / HEADS, h = bh % HEADS;
  const ushort_t* Qp = Qh + (size_t)bh * SEQ * DH;
  const ushort_t* Kp = Kh + (size_t)bh * SEQ * DH;
  const ushort_t* Vp = Vt + (size_t)bh * DH * SEQ;

  const int tid = threadIdx.x, wave = tid >> 6, lane = tid & 63;
  const int lrow = lane & 15, lk = lane >> 4;
  const int qrow0 = qt * 64 + wave * 16;

  __shared__ __align__(16) ushort_t plds[4][1024];   // per-wave 16x64 bf16 patch
  ushort_t* pw = &plds[wave][0];

  // Q fragments, resident for whole kv loop
  bf16x8 qf[2];
#pragma unroll
  for (int kk = 0; kk < 2; kk++)
    qf[kk] = *(const bf16x8*)&Qp[(size_t)(qrow0 + lrow) * DH + kk * 32 + lk * 8];

  f32x4 oacc[4];
#pragma unroll
  for (int t = 0; t < 4; t++)
#pragma unroll
    for (int r = 0; r < 4; r++) oacc[t][r] = 0.f;
  float mst[4], ls[4];
#pragma unroll
  for (int r = 0; r < 4; r++) { mst[r] = -1e30f; ls[r] = 0.f; }

  for (int kv = 0; kv < SEQ; kv += 64) {
    // ---- S = (Q K^T) * scale : 4 col-frags x (K=64 -> 2 mfma) ----
    f32x4 sacc[4];
#pragma unroll
    for (int n = 0; n < 4; n++) {
#pragma unroll
      for (int r = 0; r < 4; r++) sacc[n][r] = 0.f;
#pragma unroll
      for (int kk = 0; kk < 2; kk++) {
        bf16x8 kf = *(const bf16x8*)&Kp[(size_t)(kv + n * 16 + lrow) * DH + kk * 32 + lk * 8];
        sacc[n] = __builtin_amdgcn_mfma_f32_16x16x32_bf16(qf[kk], kf, sacc[n], 0, 0, 0);
      }
#pragma unroll
      for (int r = 0; r < 4; r++) sacc[n][r] *= SCALE;
    }
    // ---- online softmax (rows = lk*4+r, replicated across 16 lanes) ----
    float tmax[4];
#pragma unroll
    for (int r = 0; r < 4; r++)
      tmax[r] = fmaxf(fmaxf(sacc[0][r], sacc[1][r]), fmaxf(sacc[2][r], sacc[3][r]));
#pragma unroll
    for (int off = 1; off < 16; off <<= 1)
#pragma unroll
      for (int r = 0; r < 4; r++) tmax[r] = fmaxf(tmax[r], __shfl_xor(tmax[r], off));

    float fac[4], psum[4];
#pragma unroll
    for (int r = 0; r < 4; r++) {
      float mnew = fmaxf(mst[r], tmax[r]);
      fac[r] = __expf(mst[r] - mnew);
      mst[r] = mnew;
      psum[r] = 0.f;
    }
#pragma unroll
    for (int n = 0; n < 4; n++)
#pragma unroll
      for (int r = 0; r < 4; r++) {
        float p = __expf(sacc[n][r] - mst[r]);
        sacc[n][r] = p;
        psum[r] += p;
      }
#pragma unroll
    for (int off = 1; off < 16; off <<= 1)
#pragma unroll
      for (int r = 0; r < 4; r++) psum[r] += __shfl_xor(psum[r], off);
#pragma unroll
    for (int r = 0; r < 4; r++) ls[r] = ls[r] * fac[r] + psum[r];
#pragma unroll
    for (int t = 0; t < 4; t++)
#pragma unroll
      for (int r = 0; r < 4; r++) oacc[t][r] *= fac[r];

    // ---- P: acc layout -> bf16 LDS (XOR swizzle byte^((row&7)<<4)) ----
#pragma unroll
    for (int n = 0; n < 4; n++)
#pragma unroll
      for (int r = 0; r < 4; r++) {
        int rowp = lk * 4 + r, colp = n * 16 + lrow;
        int byteoff = (rowp * 128 + colp * 2) ^ ((rowp & 7) << 4);
        *(ushort_t*)((char*)pw + byteoff) = f2bf(sacc[n][r]);
      }
    asm volatile("s_waitcnt lgkmcnt(0)" ::: "memory");
    __builtin_amdgcn_sched_barrier(0);

    // ---- O += P V : A-frag from swizzled LDS, B-frag contiguous from Vt ----
    bf16x8 pf[2];
#pragma unroll
    for (int kk2 = 0; kk2 < 2; kk2++)
      pf[kk2] = *(const bf16x8*)((char*)pw +
                 ((lrow * 128 + kk2 * 64 + lk * 16) ^ ((lrow & 7) << 4)));
#pragma unroll
    for (int t = 0; t < 4; t++) {
#pragma unroll
      for (int kk2 = 0; kk2 < 2; kk2++) {
        bf16x8 vf = *(const bf16x8*)&Vp[(size_t)(t * 16 + lrow) * SEQ + kv + kk2 * 32 + lk * 8];
        oacc[t] = __builtin_amdgcn_mfma_f32_16x16x32_bf16(pf[kk2], vf, oacc[t], 0, 0, 0);
      }
    }
  }

  // ---- epilogue: O[b,n, h*64+d] bf16 ----
  __hip_bfloat16* Op = (__hip_bfloat16*)O;
#pragma unroll
  for (int r = 0; r < 4; r++) {
    const float inv = 1.f / ls[r];
    const int row = b * SEQ + qrow0 + lk * 4 + r;
#pragma unroll
    for (int t = 0; t < 4; t++) {
      const int col = h * DH + t * 16 + lrow;
      Op[(size_t)row * C_DIM + col] = __float2bfloat16(oacc[t][r] * inv);
    }
  }
}

// ---------------------------------------------------------------------------
// 5) output projection + bias + residual -> fp32 X
// ---------------------------------------------------------------------------
__global__ __launch_bounds__(256) void gemm_out_kernel(
    const ushort_t* __restrict__ Obf, const ushort_t* __restrict__ Wot,
    const float* __restrict__ bo, const float* __restrict__ query,
    float* __restrict__ X) {
  __shared__ __align__(16) ushort_t ldsA[128 * 32];
  __shared__ __align__(16) ushort_t ldsB[128 * 32];
  const int rowBase = blockIdx.y * 128;
  const int colBase = blockIdx.x * 128;
  f32x4 acc[4][4];
#pragma unroll
  for (int m = 0; m < 4; m++)
#pragma unroll
    for (int n = 0; n < 4; n++)
#pragma unroll
      for (int r = 0; r < 4; r++) acc[m][n][r] = 0.f;

  gemm128_mainloop(Obf, Wot, rowBase, colBase, ldsA, ldsB, acc);

  const int lane = threadIdx.x & 63, wave = threadIdx.x >> 6;
  const int wr = wave >> 1, wc = wave & 1;
  const int lrow = lane & 15, lk = lane >> 4;
#pragma unroll
  for (int n = 0; n < 4; n++) {
    const int col = colBase + wc * 64 + n * 16 + lrow;
    const float bval = bo[col];
#pragma unroll
    for (int m = 0; m < 4; m++) {
#pragma unroll
      for (int r = 0; r < 4; r++) {
        const int row = rowBase + wr * 64 + m * 16 + lk * 4 + r;
        const size_t idx = (size_t)row * C_DIM + col;
        X[idx] = acc[m][n][r] + bval + query[idx];
      }
    }
  }
}

// ---------------------------------------------------------------------------
// 6) LayerNorm over rows of X -> d_out (fp32)
// ---------------------------------------------------------------------------
__global__ __launch_bounds__(256) void ln_kernel(
    const float* __restrict__ X, const float* __restrict__ gamma,
    const float* __restrict__ beta, float* __restrict__ out) {
  const int row = blockIdx.x, tid = threadIdx.x;
  const float* xr = X + (size_t)row * C_DIM;
  float x0 = xr[tid], x1 = xr[tid + 256], x2 = xr[tid + 512];
  float s = x0 + x1 + x2;
  float sq = x0 * x0 + x1 * x1 + x2 * x2;
#pragma unroll
  for (int off = 32; off; off >>= 1) {
    s  += __shfl_xor(s, off);
    sq += __shfl_xor(sq, off);
  }
  __shared__ float as_[4], aq_[4];
  if ((tid & 63) == 0) { as_[tid >> 6] = s; aq_[tid >> 6] = sq; }
  __syncthreads();
  s  = as_[0] + as_[1] + as_[2] + as_[3];
  sq = aq_[0] + aq_[1] + aq_[2] + aq_[3];
  const float mean = s * (1.f / C_DIM);
  const float var  = sq * (1.f / C_DIM) - mean * mean;
  const float rstd = rsqrtf(var + EPS);
  float* orow = out + (size_t)row * C_DIM;
  orow[tid]       = (x0 - mean) * rstd * gamma[tid]       + beta[tid];
  orow[tid + 256] = (x1 - mean) * rstd * gamma[tid + 256] + beta[tid + 256];
  orow[tid + 512] = (x2 - mean) * rstd * gamma[tid + 512] + beta[tid + 512];
}

// ---------------------------------------------------------------------------
extern "C" void kernel_launch(void* const* d_in, const int* in_sizes, int n_in,
                              void* d_out, int out_size, void* d_ws, size_t ws_size,
                              hipStream_t stream) {
  (void)in_sizes; (void)n_in; (void)out_size; (void)ws_size;
  const float* query  = (const float*)d_in[0];
  const float* key_in = (const float*)d_in[1];
  const float* value  = (const float*)d_in[2];
  const float* Wq = (const float*)d_in[3];
  const float* bq = (const float*)d_in[4];
  const float* Wk = (const float*)d_in[5];
  const float* bk = (const float*)d_in[6];
  const float* Wv = (const float*)d_in[7];
  const float* bv = (const float*)d_in[8];
  const float* Wo = (const float*)d_in[9];
  const float* bo = (const float*)d_in[10];
  const float* gamma = (const float*)d_in[11];
  const float* beta  = (const float*)d_in[12];

  char* ws = (char*)d_ws;
  ushort_t* Xq  = (ushort_t*)(ws + B_XQ);
  ushort_t* Xk  = (ushort_t*)(ws + B_XK);
  ushort_t* Xv  = (ushort_t*)(ws + B_XV);
  ushort_t* Wqt = (ushort_t*)(ws + B_WQT);
  ushort_t* Wkt = (ushort_t*)(ws + B_WKT);
  ushort_t* Wvt = (ushort_t*)(ws + B_WVT);
  ushort_t* Wot = (ushort_t*)(ws + B_WOT);
  ushort_t* Qh  = (ushort_t*)(ws + B_QH);
  ushort_t* Kh  = (ushort_t*)(ws + B_KH);
  ushort_t* Vt  = (ushort_t*)(ws + B_VT);
  ushort_t* Obf = (ushort_t*)(ws + B_O);
  float*    Xr  = (float*)(ws + B_XR);
  float*    out = (float*)d_out;

  const int n4 = (int)(SZ_X / 4);            // 786432
  const int cvtBlocks = n4 / 256;            // 3072
  cvt_f32_to_bf16<<<cvtBlocks, 256, 0, stream>>>(query,  Xq, n4);
  cvt_f32_to_bf16<<<cvtBlocks, 256, 0, stream>>>(key_in, Xk, n4);
  cvt_f32_to_bf16<<<cvtBlocks, 256, 0, stream>>>(value,  Xv, n4);

  wtrans_kernel<<<dim3(24, 24, 4), 256, 0, stream>>>(Wq, Wk, Wv, Wo, Wqt, Wkt, Wvt, Wot);

  gemm_qkv_kernel<<<dim3(6, 32, 3), 256, 0, stream>>>(Xq, Xk, Xv, Wqt, Wkt, Wvt,
                                                      bq, bk, bv, Qh, Kh, Vt);

  attn_kernel<<<dim3(32, 24), 256, 0, stream>>>(Qh, Kh, Vt, Obf);

  gemm_out_kernel<<<dim3(6, 32), 256, 0, stream>>>(Obf, Wot, bo, query, Xr);

  ln_kernel<<<MTOT, 256, 0, stream>>>(Xr, gamma, beta, out);
}